// Round 2
// baseline (120.159 us; speedup 1.0000x reference)
//
#include <hip/hip_runtime.h>
#include <hip/hip_bf16.h>

#define NQ    8
#define HID   768
#define BATCH 8192
#define SPW   2                      // samples per wave
#define SPB   (4*SPW)                // samples per block (4 waves)
#define NBLK  (BATCH / SPB)          // 1024
#define TPB   256

// ---------- dtype-generic load/store ----------
template<int BF> __device__ __forceinline__ float LDV(const void* p, int i) {
    if constexpr (BF) return __bfloat162float(((const __hip_bfloat16*)p)[i]);
    else return ((const float*)p)[i];
}
// load 4 consecutive elements [4*i4 .. 4*i4+3] as float4
template<int BF> __device__ __forceinline__ float4 LD4(const void* p, int i4) {
    if constexpr (BF) {
        ushort4 v = ((const ushort4*)p)[i4];
        float4 r;
        r.x = __uint_as_float(((unsigned)v.x) << 16);
        r.y = __uint_as_float(((unsigned)v.y) << 16);
        r.z = __uint_as_float(((unsigned)v.z) << 16);
        r.w = __uint_as_float(((unsigned)v.w) << 16);
        return r;
    } else {
        return ((const float4*)p)[i4];
    }
}
// store 4 consecutive elements as one vector op
template<int BF> __device__ __forceinline__ void ST4(void* p, int i4, float4 v) {
    if constexpr (BF) {
        __hip_bfloat16 bx = __float2bfloat16(v.x);
        __hip_bfloat16 by = __float2bfloat16(v.y);
        __hip_bfloat16 bz = __float2bfloat16(v.z);
        __hip_bfloat16 bw = __float2bfloat16(v.w);
        ushort4 s;
        s.x = *(const unsigned short*)&bx;
        s.y = *(const unsigned short*)&by;
        s.z = *(const unsigned short*)&bz;
        s.w = *(const unsigned short*)&bw;
        ((ushort4*)p)[i4] = s;
    } else {
        ((float4*)p)[i4] = v;
    }
}

// ---------- fused single kernel: 1 wave = 2 samples, qubit-distributed ----------
// lane = 8*j + u : group j owns qubit j; sublane u covers columns 4*(u+8t).
template<int BF>
__device__ __forceinline__ void run_all(
    const void* hidden_, const void* W_in_, const void* b_in_,
    const void* W_out_, const void* b_out_, const void* wry_, const void* wrz_,
    const void* gamma_, const void* beta_, void* out_)
{
    const int tid  = threadIdx.x;
    const int lane = tid & 63;
    const int wv   = tid >> 6;
    const int j    = lane >> 3;       // qubit group
    const int u    = lane & 7;        // sublane within group
    const int b0   = blockIdx.x * SPB + wv * SPW;
    const int b1   = b0 + 1;

    // ---- per-lane circuit constants for qubit j (redundant, branch-free) ----
    float DA, DB, Kr, Ki;
    {
        float ry0 = LDV<BF>(wry_, j), ry1 = LDV<BF>(wry_, NQ + j);
        float rz0 = LDV<BF>(wrz_, j), rz1 = LDV<BF>(wrz_, NQ + j);
        float cA = cosf(0.5f*ry0), sA = sinf(0.5f*ry0);
        float cB = cosf(0.5f*ry1), sB = sinf(0.5f*ry1);
        float p0c = cosf(0.5f*rz0), p0s = sinf(0.5f*rz0);
        float p1c = cosf(0.5f*rz1), p1s = sinf(0.5f*rz1);
        float g00r =  cA*p0c, g00i = -cA*p0s;
        float g01r = -sA*p0c, g01i =  sA*p0s;
        float g10r =  sA*p0c, g10i =  sA*p0s;
        float g11r =  cA*p0c, g11i =  cA*p0s;
        float h00r = cB*g00r - sB*g10r, h00i = cB*g00i - sB*g10i;
        float h01r = cB*g01r - sB*g11r, h01i = cB*g01i - sB*g11i;
        float h10r = sB*g00r + cB*g10r, h10i = sB*g00i + cB*g10i;
        float h11r = sB*g01r + cB*g11r, h11i = sB*g01i + cB*g11i;
        float f00r = h00r*p1c + h00i*p1s, f00i = h00i*p1c - h00r*p1s;
        float f01r = h01r*p1c + h01i*p1s, f01i = h01i*p1c - h01r*p1s;
        float f10r = h10r*p1c - h10i*p1s, f10i = h10i*p1c + h10r*p1s;
        float f11r = h11r*p1c - h11i*p1s, f11i = h11i*p1c + h11r*p1s;
        DA = f00r*f00r + f00i*f00i - (f10r*f10r + f10i*f10i);
        DB = f01r*f01r + f01i*f01i - (f11r*f11r + f11i*f11i);
        Kr = (f00r*f01r + f00i*f01i) - (f10r*f11r + f10i*f11i);
        Ki = (f00i*f01r - f00r*f01i) - (f10i*f11r - f10r*f11i);
    }

    // ---- phase A: zz_j = <hidden_b, W_in_j> for both samples ----
    float p00=0,p01=0,p02=0,p03=0, p10=0,p11=0,p12=0,p13=0;
    const int h0b = b0 * (HID/4);
    const int h1b = b1 * (HID/4);
    const int wb  = j  * (HID/4);
    #pragma unroll
    for (int t = 0; t < 24; ++t) {
        int i4 = u + (t << 3);
        float4 w  = LD4<BF>(W_in_,   wb  + i4);
        float4 h0 = LD4<BF>(hidden_, h0b + i4);
        float4 h1 = LD4<BF>(hidden_, h1b + i4);
        p00 = fmaf(h0.x, w.x, p00); p01 = fmaf(h0.y, w.y, p01);
        p02 = fmaf(h0.z, w.z, p02); p03 = fmaf(h0.w, w.w, p03);
        p10 = fmaf(h1.x, w.x, p10); p11 = fmaf(h1.y, w.y, p11);
        p12 = fmaf(h1.z, w.z, p12); p13 = fmaf(h1.w, w.w, p13);
    }
    float acc0 = (p00 + p01) + (p02 + p03);
    float acc1 = (p10 + p11) + (p12 + p13);
    #pragma unroll
    for (int d = 1; d < 8; d <<= 1) {
        acc0 += __shfl_xor(acc0, d, 64);
        acc1 += __shfl_xor(acc1, d, 64);
    }

    // ---- circuit: one tanh/sinpi/cospi per lane per sample ----
    float binj = LDV<BF>(b_in_, j);
    float th0 = tanhf(acc0 + binj);
    float th1 = tanhf(acc1 + binj);
    float sj0 = sinpif(th0), cj0 = cospif(th0);
    float sj1 = sinpif(th1), cj1 = cospif(th1);

    float ca = 0.5f * (DA + DB), da = 0.5f * (DA - DB);
    const bool g0 = (j == 0);
    float uu0 = da * cj0, vv0 = fmaf(Kr, sj0, ca);
    float uu1 = da * cj1, vv1 = fmaf(Kr, sj1, ca);
    float MA0 = g0 ? 1.f : (vv0 + uu0), MB0 = g0 ? 1.f : (vv0 - uu0);
    float MA1 = g0 ? 1.f : (vv1 + uu1), MB1 = g0 ? 1.f : (vv1 - uu1);
    float fr0 = g0 ? 1.f : Kr, fi0 = g0 ? 0.f : (cj0 * Ki);
    float fr1 = g0 ? 1.f : Kr, fi1 = g0 ? 0.f : (cj1 * Ki);
    #pragma unroll
    for (int d = 8; d < 64; d <<= 1) {
        MA0 *= __shfl_xor(MA0, d, 64);   MA1 *= __shfl_xor(MA1, d, 64);
        MB0 *= __shfl_xor(MB0, d, 64);   MB1 *= __shfl_xor(MB1, d, 64);
        float q0r = __shfl_xor(fr0, d, 64), q0i = __shfl_xor(fi0, d, 64);
        float q1r = __shfl_xor(fr1, d, 64), q1i = __shfl_xor(fi1, d, 64);
        float n0r = fr0*q0r - fi0*q0i, n0i = fr0*q0i + fi0*q0r;
        float n1r = fr1*q1r - fi1*q1i, n1i = fr1*q1i + fi1*q1r;
        fr0 = n0r; fi0 = n0i; fr1 = n1r; fi1 = n1i;
    }
    // broadcast qubit-0 quantities from lane 0
    float DA0 = __shfl(DA, 0, 64), DB0 = __shfl(DB, 0, 64);
    float Kr0 = __shfl(Kr, 0, 64), Ki0 = __shfl(Ki, 0, 64);
    float cc00 = __shfl(cj0, 0, 64), sc00 = __shfl(sj0, 0, 64);
    float cc01 = __shfl(cj1, 0, 64), sc01 = __shfl(sj1, 0, 64);
    float meas00 = 0.5f*(1.f+cc00)*DA0*MA0 + 0.5f*(1.f-cc00)*DB0*MB0
                 + sc00*(Kr0*fr0 - Ki0*fi0);
    float meas01 = 0.5f*(1.f+cc01)*DA0*MA1 + 0.5f*(1.f-cc01)*DB0*MB1
                 + sc01*(Kr0*fr1 - Ki0*fi1);
    float measj0 = g0 ? meas00 : fmaf(cc00, uu0, vv0);
    float measj1 = g0 ? meas01 : fmaf(cc01, uu1, vv1);
    // gather meas vectors (group jj's value lives in lane 8*jj)
    float m00 = meas00;
    float m01 = __shfl(measj0,  8, 64), m02 = __shfl(measj0, 16, 64);
    float m03 = __shfl(measj0, 24, 64), m04 = __shfl(measj0, 32, 64);
    float m05 = __shfl(measj0, 40, 64), m06 = __shfl(measj0, 48, 64);
    float m07 = __shfl(measj0, 56, 64);
    float m10 = meas01;
    float m11 = __shfl(measj1,  8, 64), m12 = __shfl(measj1, 16, 64);
    float m13 = __shfl(measj1, 24, 64), m14 = __shfl(measj1, 32, 64);
    float m15 = __shfl(measj1, 40, 64), m16 = __shfl(measj1, 48, 64);
    float m17 = __shfl(measj1, 56, 64);

    // ---- phase C: y = meas @ W_out^T + b_out, LayerNorm, store ----
    // lane owns columns 12*lane .. 12*lane+11 (3 float4 groups)
    float y0v[12], y1v[12];
    float sum0 = 0.f, sq0 = 0.f, sum1 = 0.f, sq1 = 0.f;
    #pragma unroll
    for (int g = 0; g < 3; ++g) {
        float4 bo = LD4<BF>(b_out_, 3*lane + g);
        float bos[4] = {bo.x, bo.y, bo.z, bo.w};
        #pragma unroll
        for (int e = 0; e < 4; ++e) {
            int c = 12*lane + 4*g + e;
            float4 w0 = LD4<BF>(W_out_, c*2);       // W_out[c][0..3]
            float4 w1 = LD4<BF>(W_out_, c*2 + 1);   // W_out[c][4..7]
            float y0 = bos[e], y1 = bos[e];
            y0 = fmaf(m00, w0.x, y0); y0 = fmaf(m01, w0.y, y0);
            y0 = fmaf(m02, w0.z, y0); y0 = fmaf(m03, w0.w, y0);
            y0 = fmaf(m04, w1.x, y0); y0 = fmaf(m05, w1.y, y0);
            y0 = fmaf(m06, w1.z, y0); y0 = fmaf(m07, w1.w, y0);
            y1 = fmaf(m10, w0.x, y1); y1 = fmaf(m11, w0.y, y1);
            y1 = fmaf(m12, w0.z, y1); y1 = fmaf(m13, w0.w, y1);
            y1 = fmaf(m14, w1.x, y1); y1 = fmaf(m15, w1.y, y1);
            y1 = fmaf(m16, w1.z, y1); y1 = fmaf(m17, w1.w, y1);
            y0v[4*g+e] = y0; y1v[4*g+e] = y1;
            sum0 += y0; sq0 = fmaf(y0, y0, sq0);
            sum1 += y1; sq1 = fmaf(y1, y1, sq1);
        }
    }
    #pragma unroll
    for (int d = 1; d < 64; d <<= 1) {
        sum0 += __shfl_xor(sum0, d, 64);  sq0 += __shfl_xor(sq0, d, 64);
        sum1 += __shfl_xor(sum1, d, 64);  sq1 += __shfl_xor(sq1, d, 64);
    }
    float mean0 = sum0 * (1.f/HID);
    float var0  = fmaf(sq0, 1.f/HID, -mean0*mean0);
    float rstd0 = rsqrtf(var0 + 1e-5f);
    float mean1 = sum1 * (1.f/HID);
    float var1  = fmaf(sq1, 1.f/HID, -mean1*mean1);
    float rstd1 = rsqrtf(var1 + 1e-5f);
    #pragma unroll
    for (int g = 0; g < 3; ++g) {
        float4 ga = LD4<BF>(gamma_, 3*lane + g);
        float4 be = LD4<BF>(beta_,  3*lane + g);
        float4 o0, o1;
        o0.x = fmaf((y0v[4*g+0]-mean0)*rstd0, ga.x, be.x);
        o0.y = fmaf((y0v[4*g+1]-mean0)*rstd0, ga.y, be.y);
        o0.z = fmaf((y0v[4*g+2]-mean0)*rstd0, ga.z, be.z);
        o0.w = fmaf((y0v[4*g+3]-mean0)*rstd0, ga.w, be.w);
        o1.x = fmaf((y1v[4*g+0]-mean1)*rstd1, ga.x, be.x);
        o1.y = fmaf((y1v[4*g+1]-mean1)*rstd1, ga.y, be.y);
        o1.z = fmaf((y1v[4*g+2]-mean1)*rstd1, ga.z, be.z);
        o1.w = fmaf((y1v[4*g+3]-mean1)*rstd1, ga.w, be.w);
        ST4<BF>(out_, b0*(HID/4) + 3*lane + g, o0);
        ST4<BF>(out_, b1*(HID/4) + 3*lane + g, o1);
    }
}

__global__ __launch_bounds__(TPB, 4) void main_kernel(
    const void* hidden_, const void* W_in_, const void* b_in_,
    const void* W_out_, const void* b_out_, const void* wry_, const void* wrz_,
    const void* gamma_, const void* beta_, void* out_)
{
    // dtype sniff: one ballot over the first 64 words of `hidden`
    const int lane = threadIdx.x & 63;
    unsigned wrd = ((const unsigned*)hidden_)[lane];
    unsigned lo  = wrd & 0xffffu;
    unsigned e   = (lo >> 7) & 0xffu;
    bool v = (lo == 0u) || (e >= 100u && e <= 133u);
    unsigned long long mask = __ballot(v);
    int flag = (__popcll(mask) > 32) ? 1 : 0;
    if (flag)
        run_all<1>(hidden_, W_in_, b_in_, W_out_, b_out_, wry_, wrz_,
                   gamma_, beta_, out_);
    else
        run_all<0>(hidden_, W_in_, b_in_, W_out_, b_out_, wry_, wrz_,
                   gamma_, beta_, out_);
}

extern "C" void kernel_launch(void* const* d_in, const int* in_sizes, int n_in,
                              void* d_out, int out_size, void* d_ws, size_t ws_size,
                              hipStream_t stream) {
    const void* hidden = d_in[0];
    const void* W_in   = d_in[1];
    const void* b_in   = d_in[2];
    const void* W_out  = d_in[3];
    const void* b_out  = d_in[4];
    const void* wry    = d_in[5];
    const void* wrz    = d_in[6];
    const void* gamma  = d_in[7];
    const void* beta   = d_in[8];
    (void)d_ws; (void)ws_size;
    main_kernel<<<NBLK, TPB, 0, stream>>>(hidden, W_in, b_in, W_out, b_out,
                                          wry, wrz, gamma, beta, d_out);
}

// Round 3
// 117.552 us; speedup vs baseline: 1.0222x; 1.0222x over previous
//
#include <hip/hip_runtime.h>
#include <hip/hip_bf16.h>

#define NQ    8
#define HID   768
#define BATCH 8192
#define SPB   4                      // 4 waves/block, 1 sample per wave
#define NBLK  (BATCH / SPB)          // 2048
#define TPB   256

// ---------- dtype-generic load/store ----------
template<int BF> __device__ __forceinline__ float LDV(const void* p, int i) {
    if constexpr (BF) return __bfloat162float(((const __hip_bfloat16*)p)[i]);
    else return ((const float*)p)[i];
}
// load 4 consecutive elements [4*i4 .. 4*i4+3] as float4
template<int BF> __device__ __forceinline__ float4 LD4(const void* p, int i4) {
    if constexpr (BF) {
        ushort4 v = ((const ushort4*)p)[i4];
        float4 r;
        r.x = __uint_as_float(((unsigned)v.x) << 16);
        r.y = __uint_as_float(((unsigned)v.y) << 16);
        r.z = __uint_as_float(((unsigned)v.z) << 16);
        r.w = __uint_as_float(((unsigned)v.w) << 16);
        return r;
    } else {
        return ((const float4*)p)[i4];
    }
}
// store 4 consecutive elements as one vector op
template<int BF> __device__ __forceinline__ void ST4(void* p, int i4, float4 v) {
    if constexpr (BF) {
        __hip_bfloat16 bx = __float2bfloat16(v.x);
        __hip_bfloat16 by = __float2bfloat16(v.y);
        __hip_bfloat16 bz = __float2bfloat16(v.z);
        __hip_bfloat16 bw = __float2bfloat16(v.w);
        ushort4 s;
        s.x = *(const unsigned short*)&bx;
        s.y = *(const unsigned short*)&by;
        s.z = *(const unsigned short*)&bz;
        s.w = *(const unsigned short*)&bw;
        ((ushort4*)p)[i4] = s;
    } else {
        ((float4*)p)[i4] = v;
    }
}

// ---------- fused single kernel: 1 wave = 1 sample ----------
// Phase A: lane owns float4 quads {lane, 64+lane, 128+lane} of the row
//          (unit-stride 1KB per load instruction, no redundancy),
//          accumulates partials for ALL 8 qubits, then a 10-shfl
//          multi-value butterfly lands z_j in group j (lanes 8j..8j+7).
// Circuit: group j (lane>>3) owns qubit j, identical to prior rounds.
// Phase C: same quad ownership -> unit-stride 1KB stores.
template<int BF>
__device__ __forceinline__ void run_all(
    const void* hidden_, const void* W_in_, const void* b_in_,
    const void* W_out_, const void* b_out_, const void* wry_, const void* wrz_,
    const void* gamma_, const void* beta_, void* out_)
{
    const int tid  = threadIdx.x;
    const int lane = tid & 63;
    const int wv   = tid >> 6;
    const int j    = lane >> 3;       // qubit group for circuit phase
    const int b    = blockIdx.x * SPB + wv;

    // ---- per-lane circuit constants for qubit j (redundant, branch-free) ----
    float DA, DB, Kr, Ki;
    {
        float ry0 = LDV<BF>(wry_, j), ry1 = LDV<BF>(wry_, NQ + j);
        float rz0 = LDV<BF>(wrz_, j), rz1 = LDV<BF>(wrz_, NQ + j);
        float cA = cosf(0.5f*ry0), sA = sinf(0.5f*ry0);
        float cB = cosf(0.5f*ry1), sB = sinf(0.5f*ry1);
        float p0c = cosf(0.5f*rz0), p0s = sinf(0.5f*rz0);
        float p1c = cosf(0.5f*rz1), p1s = sinf(0.5f*rz1);
        float g00r =  cA*p0c, g00i = -cA*p0s;
        float g01r = -sA*p0c, g01i =  sA*p0s;
        float g10r =  sA*p0c, g10i =  sA*p0s;
        float g11r =  cA*p0c, g11i =  cA*p0s;
        float h00r = cB*g00r - sB*g10r, h00i = cB*g00i - sB*g10i;
        float h01r = cB*g01r - sB*g11r, h01i = cB*g01i - sB*g11i;
        float h10r = sB*g00r + cB*g10r, h10i = sB*g00i + cB*g10i;
        float h11r = sB*g01r + cB*g11r, h11i = sB*g01i + cB*g11i;
        float f00r = h00r*p1c + h00i*p1s, f00i = h00i*p1c - h00r*p1s;
        float f01r = h01r*p1c + h01i*p1s, f01i = h01i*p1c - h01r*p1s;
        float f10r = h10r*p1c - h10i*p1s, f10i = h10i*p1c + h10r*p1s;
        float f11r = h11r*p1c - h11i*p1s, f11i = h11i*p1c + h11r*p1s;
        DA = f00r*f00r + f00i*f00i - (f10r*f10r + f10i*f10i);
        DB = f01r*f01r + f01i*f01i - (f11r*f11r + f11i*f11i);
        Kr = (f00r*f01r + f00i*f01i) - (f10r*f11r + f10i*f11i);
        Ki = (f00i*f01r - f00r*f01i) - (f10i*f11r - f10r*f11i);
    }

    // ---- phase A: partial dots for all 8 qubits over this lane's 12 cols ----
    float p[NQ];
    #pragma unroll
    for (int q = 0; q < NQ; ++q) p[q] = 0.f;
    const int hb = b * (HID/4);
    #pragma unroll
    for (int t = 0; t < 3; ++t) {
        const int q4 = (t << 6) + lane;             // float4 index in row
        float4 h = LD4<BF>(hidden_, hb + q4);
        #pragma unroll
        for (int jj = 0; jj < NQ; ++jj) {
            float4 w = LD4<BF>(W_in_, jj*(HID/4) + q4);
            p[jj] = fmaf(h.x, w.x, p[jj]);
            p[jj] = fmaf(h.y, w.y, p[jj]);
            p[jj] = fmaf(h.z, w.z, p[jj]);
            p[jj] = fmaf(h.w, w.w, p[jj]);
        }
    }
    // ---- multi-value butterfly: land z_j in lanes with g==j ----
    const bool mb0 = ((lane >> 3) & 1) != 0;
    const bool mb1 = ((lane >> 4) & 1) != 0;
    const bool mb2 = ((lane >> 5) & 1) != 0;
    float np[4];
    #pragma unroll
    for (int k = 0; k < 4; ++k) {
        float sent = mb0 ? p[2*k]   : p[2*k+1];     // slot the partner keeps
        float keep = mb0 ? p[2*k+1] : p[2*k];
        np[k] = keep + __shfl_xor(sent, 8, 64);
    }
    float nq[2];
    #pragma unroll
    for (int k = 0; k < 2; ++k) {
        float sent = mb1 ? np[2*k]   : np[2*k+1];
        float keep = mb1 ? np[2*k+1] : np[2*k];
        nq[k] = keep + __shfl_xor(sent, 16, 64);
    }
    float z;
    {
        float sent = mb2 ? nq[0] : nq[1];
        float keep = mb2 ? nq[1] : nq[0];
        z = keep + __shfl_xor(sent, 32, 64);
    }
    z += __shfl_xor(z, 1, 64);
    z += __shfl_xor(z, 2, 64);
    z += __shfl_xor(z, 4, 64);

    // ---- circuit: one tanh/sinpi/cospi per lane ----
    float zb = z + LDV<BF>(b_in_, j);
    float th = tanhf(zb);
    float sj = sinpif(th), cj = cospif(th);

    float ca = 0.5f * (DA + DB), da = 0.5f * (DA - DB);
    const bool g0 = (j == 0);
    float uu = da * cj;
    float vv = fmaf(Kr, sj, ca);
    float MA = g0 ? 1.f : (vv + uu), MB = g0 ? 1.f : (vv - uu);
    float fr = g0 ? 1.f : Kr, fi = g0 ? 0.f : (cj * Ki);
    #pragma unroll
    for (int d = 8; d < 64; d <<= 1) {
        MA *= __shfl_xor(MA, d, 64);
        MB *= __shfl_xor(MB, d, 64);
        float qr = __shfl_xor(fr, d, 64);
        float qi = __shfl_xor(fi, d, 64);
        float nr = fr*qr - fi*qi;
        float ni = fr*qi + fi*qr;
        fr = nr; fi = ni;
    }
    float DA0 = __shfl(DA, 0, 64), DB0 = __shfl(DB, 0, 64);
    float Kr0 = __shfl(Kr, 0, 64), Ki0 = __shfl(Ki, 0, 64);
    float cc0 = __shfl(cj, 0, 64), sc0 = __shfl(sj, 0, 64);
    float meas0 = 0.5f*(1.f+cc0)*DA0*MA + 0.5f*(1.f-cc0)*DB0*MB
                + sc0*(Kr0*fr - Ki0*fi);
    float measj = g0 ? meas0 : fmaf(cc0, uu, vv);
    float m0 = meas0;
    float m1 = __shfl(measj,  8, 64), m2 = __shfl(measj, 16, 64);
    float m3 = __shfl(measj, 24, 64), m4 = __shfl(measj, 32, 64);
    float m5 = __shfl(measj, 40, 64), m6 = __shfl(measj, 48, 64);
    float m7 = __shfl(measj, 56, 64);

    // ---- phase C: y = meas @ W_out^T + b_out, LayerNorm, store ----
    // lane owns quads q = 64t + lane (t = 0..2): cols 4q .. 4q+3
    float yv[12];
    float sum = 0.f, sq = 0.f;
    #pragma unroll
    for (int t = 0; t < 3; ++t) {
        const int q4 = (t << 6) + lane;
        float4 bo = LD4<BF>(b_out_, q4);
        float bos[4] = {bo.x, bo.y, bo.z, bo.w};
        #pragma unroll
        for (int e = 0; e < 4; ++e) {
            int c = 4*q4 + e;
            float4 w0 = LD4<BF>(W_out_, c*2);       // W_out[c][0..3]
            float4 w1 = LD4<BF>(W_out_, c*2 + 1);   // W_out[c][4..7]
            float y = bos[e];
            y = fmaf(m0, w0.x, y); y = fmaf(m1, w0.y, y);
            y = fmaf(m2, w0.z, y); y = fmaf(m3, w0.w, y);
            y = fmaf(m4, w1.x, y); y = fmaf(m5, w1.y, y);
            y = fmaf(m6, w1.z, y); y = fmaf(m7, w1.w, y);
            yv[4*t+e] = y;
            sum += y;
            sq = fmaf(y, y, sq);
        }
    }
    #pragma unroll
    for (int d = 1; d < 64; d <<= 1) {
        sum += __shfl_xor(sum, d, 64);
        sq  += __shfl_xor(sq,  d, 64);
    }
    float mean = sum * (1.f/HID);
    float var  = fmaf(sq, 1.f/HID, -mean*mean);
    float rstd = rsqrtf(var + 1e-5f);
    #pragma unroll
    for (int t = 0; t < 3; ++t) {
        const int q4 = (t << 6) + lane;
        float4 ga = LD4<BF>(gamma_, q4);
        float4 be = LD4<BF>(beta_,  q4);
        float4 o;
        o.x = fmaf((yv[4*t+0]-mean)*rstd, ga.x, be.x);
        o.y = fmaf((yv[4*t+1]-mean)*rstd, ga.y, be.y);
        o.z = fmaf((yv[4*t+2]-mean)*rstd, ga.z, be.z);
        o.w = fmaf((yv[4*t+3]-mean)*rstd, ga.w, be.w);
        ST4<BF>(out_, hb + q4, o);                  // unit-stride 1KB store
    }
}

__global__ __launch_bounds__(TPB, 4) void main_kernel(
    const void* hidden_, const void* W_in_, const void* b_in_,
    const void* W_out_, const void* b_out_, const void* wry_, const void* wrz_,
    const void* gamma_, const void* beta_, void* out_)
{
    // dtype sniff: one ballot over the first 64 words of `hidden`
    const int lane = threadIdx.x & 63;
    unsigned wrd = ((const unsigned*)hidden_)[lane];
    unsigned lo  = wrd & 0xffffu;
    unsigned e   = (lo >> 7) & 0xffu;
    bool v = (lo == 0u) || (e >= 100u && e <= 133u);
    unsigned long long mask = __ballot(v);
    int flag = (__popcll(mask) > 32) ? 1 : 0;
    if (flag)
        run_all<1>(hidden_, W_in_, b_in_, W_out_, b_out_, wry_, wrz_,
                   gamma_, beta_, out_);
    else
        run_all<0>(hidden_, W_in_, b_in_, W_out_, b_out_, wry_, wrz_,
                   gamma_, beta_, out_);
}

extern "C" void kernel_launch(void* const* d_in, const int* in_sizes, int n_in,
                              void* d_out, int out_size, void* d_ws, size_t ws_size,
                              hipStream_t stream) {
    const void* hidden = d_in[0];
    const void* W_in   = d_in[1];
    const void* b_in   = d_in[2];
    const void* W_out  = d_in[3];
    const void* b_out  = d_in[4];
    const void* wry    = d_in[5];
    const void* wrz    = d_in[6];
    const void* gamma  = d_in[7];
    const void* beta   = d_in[8];
    (void)d_ws; (void)ws_size;
    main_kernel<<<NBLK, TPB, 0, stream>>>(hidden, W_in, b_in, W_out, b_out,
                                          wry, wrz, gamma, beta, d_out);
}